// Round 1
// baseline (276.522 us; speedup 1.0000x reference)
//
#include <hip/hip_runtime.h>

typedef __attribute__((ext_vector_type(8))) short short8;
typedef __attribute__((ext_vector_type(4))) float float4_;

__device__ __forceinline__ unsigned short f2bf(float f) {
    unsigned u = __float_as_uint(f);
    u += 0x7FFFu + ((u >> 16) & 1u);   // round-to-nearest-even
    return (unsigned short)(u >> 16);
}

// ---------------------------------------------------------------------------
// Kernel 0: convert weights fp32 -> bf16, transposed to [N][K] so MFMA
// B-fragments are one contiguous 16B load per lane. W3 padded to N=16 (zeros).
// w1t: [6][256][192], w2t: [6][256][256], w3t: [6][16][256]
// ---------------------------------------------------------------------------
__global__ void prep_weights(const float* __restrict__ W1,
                             const float* __restrict__ W2,
                             const float* __restrict__ W3,
                             unsigned short* __restrict__ w1t,
                             unsigned short* __restrict__ w2t,
                             unsigned short* __restrict__ w3t) {
    int id = blockIdx.x * 256 + threadIdx.x;
    if (id < 294912) {                       // 6*256*192
        int t = id / 49152, r = id % 49152;
        int n = r / 192, k = r % 192;
        w1t[id] = f2bf(W1[(size_t)t * 49152 + k * 256 + n]);
    } else if (id < 688128) {                // + 6*256*256
        int i2 = id - 294912;
        int t = i2 / 65536, r = i2 % 65536;
        int n = r / 256, k = r % 256;
        w2t[i2] = f2bf(W2[(size_t)t * 65536 + k * 256 + n]);
    } else if (id < 712704) {                // + 6*16*256
        int i3 = id - 688128;
        int t = i3 / 4096, r = i3 % 4096;
        int n = r / 256, k = r % 256;
        w3t[i3] = (n < 3) ? f2bf(W3[(size_t)t * 768 + k * 3 + n]) : (unsigned short)0;
    }
}

// ---------------------------------------------------------------------------
// Kernel 1: ROI-align (bilinear, mode=nearest clamp) 32x32 patch mean.
// grid = G*8 blocks; block handles one garment x 8 channels; 32 lanes per
// channel each own one x-column, loop 32 rows, shuffle-reduce over 32 lanes.
// ---------------------------------------------------------------------------
__global__ void garf_kernel(const float* __restrict__ imgs,
                            const float* __restrict__ pros,
                            const int* __restrict__ imgbatch,
                            float* __restrict__ garf) {
    int g = blockIdx.x >> 3;
    int cblk = blockIdx.x & 7;
    int c = cblk * 8 + (threadIdx.x >> 5);
    int j = threadIdx.x & 31;
    int b = imgbatch[g];
    float cx = pros[g * 2 + 0], cy = pros[g * 2 + 1];

    float x = cx - 16.0f + (float)j + 0.5f;
    float xf = floorf(x);
    float wx1 = x - xf, wx0 = 1.0f - wx1;
    int ix0 = (int)xf, ix1 = ix0 + 1;
    ix0 = min(max(ix0, 0), 191); ix1 = min(max(ix1, 0), 191);

    const float* base = imgs + (size_t)(b * 64 + c) * (192 * 192);
    float sum = 0.0f;
    for (int i = 0; i < 32; ++i) {
        float y = cy - 16.0f + (float)i + 0.5f;
        float yf = floorf(y);
        float wy1 = y - yf, wy0 = 1.0f - wy1;
        int iy0 = (int)yf, iy1 = iy0 + 1;
        iy0 = min(max(iy0, 0), 191); iy1 = min(max(iy1, 0), 191);
        const float* r0 = base + iy0 * 192;
        const float* r1 = base + iy1 * 192;
        sum += wy0 * (wx0 * r0[ix0] + wx1 * r0[ix1]) +
               wy1 * (wx0 * r1[ix0] + wx1 * r1[ix1]);
    }
    for (int s = 16; s >= 1; s >>= 1) sum += __shfl_xor(sum, s);
    if (j == 0) garf[g * 64 + c] = sum * (1.0f / 1024.0f);
}

// ---------------------------------------------------------------------------
// Kernel 2: fused MoE MLP. One block = 64 vertices of one type.
// feat[64x192] gathered+bf16 into LDS (XOR-swizzled 16B units), then
// L1 (K=192) -> relu -> LDS -> L2 (K=256) -> relu -> LDS -> L3 (K=256, N=16
// zero-padded W3, K split across 4 waves, LDS reduce) -> scatter to out.
// MFMA 16x16x32 bf16: A[m=lane&15][k=q*8+j], B[k=q*8+j][n=lane&15],
// D[m=q*4+r][n=lane&15].
// ---------------------------------------------------------------------------
struct MoEArgs {
    const float* x_verts;
    const int* gar;
    const int* idx[6];
    const unsigned short* w1t;
    const unsigned short* w2t;
    const unsigned short* w3t;
    const float* garf;
    float* out;
    int cnt[6];
    int tile_end[6];
};

__global__ __launch_bounds__(256) void moe_kernel(MoEArgs a) {
    __shared__ __align__(16) char smem[24576 + 32768 + 512];
    char* sA = smem;                 // 64 x 192 bf16, row stride 384B, swizzled
    char* sH = smem + 24576;         // 64 x 256 bf16, row stride 512B, swizzled
    float* sO = (float*)smem;        // 4 x 64 x 16 f32 (aliases sA; sA dead by then)
    int* sidx = (int*)(smem + 24576 + 32768);
    int* sg = sidx + 64;

    const int tid = threadIdx.x;
    int bt = blockIdx.x;
    int t = 0;
    while (t < 5 && bt >= a.tile_end[t]) ++t;
    const int tile = bt - (t ? a.tile_end[t - 1] : 0);
    const int cnt = a.cnt[t];
    const int i0 = tile * 64;
    const int* idx = a.idx[t];

    if (tid < 64) {
        int m = i0 + tid;
        if (m > cnt - 1) m = cnt - 1;
        int vid = idx[m];
        sidx[tid] = vid;
        sg[tid] = a.gar[vid];
    }
    __syncthreads();

    // ---- stage feat tile: 64 rows x 24 units(8 bf16) ----
    for (int e = tid; e < 1536; e += 256) {
        int m = e / 24, u = e % 24;
        const float* src;
        if (u < 16) src = a.x_verts + (size_t)sidx[m] * 128 + u * 8;
        else        src = a.garf + sg[m] * 64 + (u - 16) * 8;
        float4 v0 = ((const float4*)src)[0];
        float4 v1 = ((const float4*)src)[1];
        short8 pk;
        pk[0] = f2bf(v0.x); pk[1] = f2bf(v0.y); pk[2] = f2bf(v0.z); pk[3] = f2bf(v0.w);
        pk[4] = f2bf(v1.x); pk[5] = f2bf(v1.y); pk[6] = f2bf(v1.z); pk[7] = f2bf(v1.w);
        *(short8*)(sA + m * 384 + ((u ^ (m & 7)) * 16)) = pk;
    }
    __syncthreads();

    const int lane = tid & 63, w = tid >> 6, q = lane >> 4, l = lane & 15;

    // ---- layer 1: [64x192] @ [192x256] ----
    float4_ acc[4][4] = {};
    const unsigned short* w1 = a.w1t + (size_t)t * 49152;
    for (int ks = 0; ks < 6; ++ks) {
        short8 af[4], bfr[4];
        for (int mt = 0; mt < 4; ++mt) {
            int row = mt * 16 + l;
            af[mt] = *(const short8*)(sA + row * 384 + (((ks * 4 + q) ^ (row & 7)) * 16));
        }
        for (int nt = 0; nt < 4; ++nt) {
            int n = w * 64 + nt * 16 + l;
            bfr[nt] = *(const short8*)(w1 + n * 192 + ks * 32 + q * 8);
        }
        for (int mt = 0; mt < 4; ++mt)
            for (int nt = 0; nt < 4; ++nt)
                acc[mt][nt] = __builtin_amdgcn_mfma_f32_16x16x32_bf16(
                    af[mt], bfr[nt], acc[mt][nt], 0, 0, 0);
    }
    // relu -> h1 into sH (each wave owns its n-range; no race)
    for (int mt = 0; mt < 4; ++mt)
        for (int nt = 0; nt < 4; ++nt) {
            int n = w * 64 + nt * 16 + l;
            for (int r = 0; r < 4; ++r) {
                int m = mt * 16 + q * 4 + r;
                unsigned short b = f2bf(fmaxf(acc[mt][nt][r], 0.0f));
                *(unsigned short*)(sH + m * 512 + (((n >> 3) ^ (m & 7)) * 16) + (n & 7) * 2) = b;
            }
        }
    __syncthreads();

    // ---- layer 2: [64x256] @ [256x256] ----
    float4_ acc2[4][4] = {};
    const unsigned short* w2 = a.w2t + (size_t)t * 65536;
    for (int ks = 0; ks < 8; ++ks) {
        short8 af[4], bfr[4];
        for (int mt = 0; mt < 4; ++mt) {
            int row = mt * 16 + l;
            af[mt] = *(const short8*)(sH + row * 512 + (((ks * 4 + q) ^ (row & 7)) * 16));
        }
        for (int nt = 0; nt < 4; ++nt) {
            int n = w * 64 + nt * 16 + l;
            bfr[nt] = *(const short8*)(w2 + n * 256 + ks * 32 + q * 8);
        }
        for (int mt = 0; mt < 4; ++mt)
            for (int nt = 0; nt < 4; ++nt)
                acc2[mt][nt] = __builtin_amdgcn_mfma_f32_16x16x32_bf16(
                    af[mt], bfr[nt], acc2[mt][nt], 0, 0, 0);
    }
    __syncthreads();   // all h1 reads done before overwriting sH with h2
    for (int mt = 0; mt < 4; ++mt)
        for (int nt = 0; nt < 4; ++nt) {
            int n = w * 64 + nt * 16 + l;
            for (int r = 0; r < 4; ++r) {
                int m = mt * 16 + q * 4 + r;
                unsigned short b = f2bf(fmaxf(acc2[mt][nt][r], 0.0f));
                *(unsigned short*)(sH + m * 512 + (((n >> 3) ^ (m & 7)) * 16) + (n & 7) * 2) = b;
            }
        }
    __syncthreads();

    // ---- layer 3: [64x256] @ [256x16(zero-padded 3)], K split over 4 waves ----
    float4_ acc3[4] = {};
    const unsigned short* w3 = a.w3t + (size_t)t * 4096;
    for (int s2 = 0; s2 < 2; ++s2) {
        int ks = w * 2 + s2;
        short8 bf3 = *(const short8*)(w3 + l * 256 + ks * 32 + q * 8);
        for (int mt = 0; mt < 4; ++mt) {
            int row = mt * 16 + l;
            short8 af = *(const short8*)(sH + row * 512 + (((ks * 4 + q) ^ (row & 7)) * 16));
            acc3[mt] = __builtin_amdgcn_mfma_f32_16x16x32_bf16(af, bf3, acc3[mt], 0, 0, 0);
        }
    }
    float* sOw = sO + w * 1024;
    for (int mt = 0; mt < 4; ++mt)
        for (int r = 0; r < 4; ++r) {
            int m = mt * 16 + q * 4 + r;
            sOw[m * 16 + l] = acc3[mt][r];
        }
    __syncthreads();

    if (tid < 192) {
        int m = tid / 3, j = tid - m * 3;
        if (i0 + m < cnt) {
            float s = sO[m * 16 + j] + sO[1024 + m * 16 + j] +
                      sO[2048 + m * 16 + j] + sO[3072 + m * 16 + j];
            a.out[(size_t)sidx[m] * 3 + j] = s;
        }
    }
}

// ---------------------------------------------------------------------------
extern "C" void kernel_launch(void* const* d_in, const int* in_sizes, int n_in,
                              void* d_out, int out_size, void* d_ws, size_t ws_size,
                              hipStream_t stream) {
    const float* imgs    = (const float*)d_in[0];
    const float* pros    = (const float*)d_in[1];
    const float* x_verts = (const float*)d_in[2];
    const float* W1      = (const float*)d_in[3];
    const float* W2      = (const float*)d_in[4];
    const float* W3      = (const float*)d_in[5];
    const int* imgbatch  = (const int*)d_in[6];
    const int* gar       = (const int*)d_in[7];

    // ws layout (16B-aligned): w1t | w2t | w3t | garf
    unsigned short* w1t = (unsigned short*)d_ws;                       // 589824 B
    unsigned short* w2t = (unsigned short*)((char*)d_ws + 589824);     // 786432 B
    unsigned short* w3t = (unsigned short*)((char*)d_ws + 1376256);    // 49152 B
    float* garf         = (float*)((char*)d_ws + 1425408);             // 6144 B

    prep_weights<<<2784, 256, 0, stream>>>(W1, W2, W3, w1t, w2t, w3t);
    garf_kernel<<<24 * 8, 256, 0, stream>>>(imgs, pros, imgbatch, garf);

    MoEArgs a;
    a.x_verts = x_verts;
    a.gar = gar;
    for (int t = 0; t < 6; ++t) a.idx[t] = (const int*)d_in[8 + t];
    a.w1t = w1t; a.w2t = w2t; a.w3t = w3t;
    a.garf = garf;
    a.out = (float*)d_out;
    int tiles = 0;
    for (int t = 0; t < 6; ++t) {
        a.cnt[t] = in_sizes[8 + t];
        tiles += (a.cnt[t] + 63) / 64;
        a.tile_end[t] = tiles;
    }
    moe_kernel<<<tiles, 256, 0, stream>>>(a);
}

// Round 2
// 265.322 us; speedup vs baseline: 1.0422x; 1.0422x over previous
//
#include <hip/hip_runtime.h>

typedef __attribute__((ext_vector_type(8))) short short8;
typedef __attribute__((ext_vector_type(4))) float float4_;

__device__ __forceinline__ unsigned short f2bf(float f) {
    unsigned u = __float_as_uint(f);
    u += 0x7FFFu + ((u >> 16) & 1u);   // round-to-nearest-even
    return (unsigned short)(u >> 16);
}

#define GARF_BLOCKS 1536   // G(24) * C(64)
#define PREP_BLOCKS 2784   // ceil(712704 / 256)

// ---------------------------------------------------------------------------
// Fused kernel 0: (a) ROI-align 32x32 bilinear patch means -> garf[G][C]
//                 (b) weights fp32 -> bf16, transposed to [N][K]
// garf part: one block per (g,c); 4 samples/thread; block reduce.
// prep part: coalesced source reads, scattered bf16 writes (stores don't stall)
// ---------------------------------------------------------------------------
__global__ void prep_garf(const float* __restrict__ imgs,
                          const float* __restrict__ pros,
                          const int* __restrict__ imgbatch,
                          const float* __restrict__ W1,
                          const float* __restrict__ W2,
                          const float* __restrict__ W3,
                          unsigned short* __restrict__ w1t,
                          unsigned short* __restrict__ w2t,
                          unsigned short* __restrict__ w3t,
                          float* __restrict__ garf) {
    const int tid = threadIdx.x;
    if (blockIdx.x < GARF_BLOCKS) {
        __shared__ float part[4];
        int pc = blockIdx.x;
        int g = pc >> 6, c = pc & 63;
        int b = imgbatch[g];
        float cx = pros[g * 2 + 0], cy = pros[g * 2 + 1];
        int i = tid >> 3;                 // row 0..31
        int j0 = (tid & 7) * 4;           // 4 columns per thread
        float y = cy - 16.0f + (float)i + 0.5f;
        float yf = floorf(y);
        float wy1 = y - yf, wy0 = 1.0f - wy1;
        int iy0 = min(max((int)yf, 0), 191), iy1 = min(max((int)yf + 1, 0), 191);
        const float* base = imgs + (size_t)(b * 64 + c) * 36864;
        const float* r0 = base + iy0 * 192;
        const float* r1 = base + iy1 * 192;
        float sum = 0.0f;
#pragma unroll
        for (int jj = 0; jj < 4; ++jj) {
            float x = cx - 16.0f + (float)(j0 + jj) + 0.5f;
            float xf = floorf(x);
            float wx1 = x - xf, wx0 = 1.0f - wx1;
            int ix0 = min(max((int)xf, 0), 191), ix1 = min(max((int)xf + 1, 0), 191);
            sum += wy0 * (wx0 * r0[ix0] + wx1 * r0[ix1]) +
                   wy1 * (wx0 * r1[ix0] + wx1 * r1[ix1]);
        }
        for (int s = 32; s >= 1; s >>= 1) sum += __shfl_xor(sum, s);
        if ((tid & 63) == 0) part[tid >> 6] = sum;
        __syncthreads();
        if (tid == 0)
            garf[g * 64 + c] = (part[0] + part[1] + part[2] + part[3]) * (1.0f / 1024.0f);
    } else {
        int id = (blockIdx.x - GARF_BLOCKS) * 256 + tid;
        if (id < 294912) {                       // W1: 6*192*256, src [t][k][n]
            int t = id / 49152, r = id % 49152;
            int k = r >> 8, n = r & 255;
            w1t[t * 49152 + n * 192 + k] = f2bf(W1[id]);
        } else if (id < 688128) {                // W2: 6*256*256
            int i2 = id - 294912;
            int t = i2 >> 16, r = i2 & 65535;
            int k = r >> 8, n = r & 255;
            w2t[t * 65536 + n * 256 + k] = f2bf(W2[i2]);
        } else if (id < 712704) {                // w3t dest: 6*16*256 (n>=3 zero)
            int i3 = id - 688128;
            int t = i3 >> 12, r = i3 & 4095;
            int n = r >> 8, k = r & 255;
            w3t[i3] = (n < 3) ? f2bf(W3[t * 768 + k * 3 + n]) : (unsigned short)0;
        }
    }
}

// ---------------------------------------------------------------------------
// Kernel 1: fused MoE MLP, transposed compute (weights = A operand, vertices
// = B/n operand). One block = 64 vertices of one type; feat and hidden share
// one aliased 32KB LDS buffer (phases barrier-separated) -> 4 blocks/CU.
// MFMA 16x16x32 bf16: A[m=lane&15][k=q*8+j], B[k=q*8+j][n=lane&15],
// D[m=q*4+r][n=lane&15] => register dim r runs along HIDDEN dim: packed
// 4xbf16 ds_write_b64 epilogue; layer3 writes out directly from registers.
// ---------------------------------------------------------------------------
struct MoEArgs {
    const float* x_verts;
    const int* gar;
    const int* idx[6];
    const unsigned short* w1t;
    const unsigned short* w2t;
    const unsigned short* w3t;
    const float* garf;
    float* out;
    int cnt[6];
    int tile_end[6];
};

__global__ __launch_bounds__(256, 4) void moe_kernel(MoEArgs a) {
    __shared__ __align__(16) char smem[32768 + 512];
    char* sF = smem;                    // feat 64x384B, then h 64x512B (aliased)
    int* sidx = (int*)(smem + 32768);
    int* sg = sidx + 64;

    const int tid = threadIdx.x;
    int bt = blockIdx.x;
    int t = 0;
    while (t < 5 && bt >= a.tile_end[t]) ++t;
    const int tile = bt - (t ? a.tile_end[t - 1] : 0);
    const int cnt = a.cnt[t];
    const int i0 = tile * 64;
    const int* idx = a.idx[t];

    if (tid < 64) {
        int m = i0 + tid;
        if (m > cnt - 1) m = cnt - 1;
        int vid = idx[m];
        sidx[tid] = vid;
        sg[tid] = a.gar[vid];
    }
    __syncthreads();

    // ---- stage feat tile: 64 rows x 24 16B-units, swizzle u^(row&7) ----
    for (int e = tid; e < 1536; e += 256) {
        int m = e / 24, u = e % 24;
        const float* src;
        if (u < 16) src = a.x_verts + (size_t)sidx[m] * 128 + u * 8;
        else        src = a.garf + sg[m] * 64 + (u - 16) * 8;
        float4 v0 = ((const float4*)src)[0];
        float4 v1 = ((const float4*)src)[1];
        short8 pk;
        pk[0] = f2bf(v0.x); pk[1] = f2bf(v0.y); pk[2] = f2bf(v0.z); pk[3] = f2bf(v0.w);
        pk[4] = f2bf(v1.x); pk[5] = f2bf(v1.y); pk[6] = f2bf(v1.z); pk[7] = f2bf(v1.w);
        *(short8*)(sF + m * 384 + ((u ^ (m & 7)) * 16)) = pk;
    }
    __syncthreads();

    const int lane = tid & 63, w = tid >> 6, q = lane >> 4, l = lane & 15;

    // ---- layer 1: H1^T[256 hid][64 v] = W1^T @ F^T, K=192 ----
    float4_ acc[4][4] = {};
    const unsigned short* w1 = a.w1t + (size_t)t * 49152;
    for (int ks = 0; ks < 6; ++ks) {
        short8 af[4], bfr[4];
        for (int mt = 0; mt < 4; ++mt) {
            int hid = w * 64 + mt * 16 + l;
            af[mt] = *(const short8*)(w1 + hid * 192 + ks * 32 + q * 8);
        }
        for (int nt = 0; nt < 4; ++nt) {
            int v = nt * 16 + l;
            bfr[nt] = *(const short8*)(sF + v * 384 + (((ks * 4 + q) ^ (v & 7)) * 16));
        }
        for (int mt = 0; mt < 4; ++mt)
            for (int nt = 0; nt < 4; ++nt)
                acc[mt][nt] = __builtin_amdgcn_mfma_f32_16x16x32_bf16(
                    af[mt], bfr[nt], acc[mt][nt], 0, 0, 0);
    }
    __syncthreads();   // all feat reads done before overwriting sF with h1

    // relu -> h1: row v stride 512B, 16B-unit swizzle ku^(v&7), 8B granule
    for (int mt = 0; mt < 4; ++mt)
        for (int nt = 0; nt < 4; ++nt) {
            int v = nt * 16 + l;
            int hu8 = w * 16 + mt * 4 + q;         // hid/4
            int ku16 = hu8 >> 1, par = hu8 & 1;
            uint2 pk;
            pk.x = (unsigned)f2bf(fmaxf(acc[mt][nt][0], 0.0f)) |
                   ((unsigned)f2bf(fmaxf(acc[mt][nt][1], 0.0f)) << 16);
            pk.y = (unsigned)f2bf(fmaxf(acc[mt][nt][2], 0.0f)) |
                   ((unsigned)f2bf(fmaxf(acc[mt][nt][3], 0.0f)) << 16);
            *(uint2*)(sF + v * 512 + ((ku16 ^ (v & 7)) * 16) + par * 8) = pk;
        }
    __syncthreads();

    // ---- layer 2: H2^T = W2^T @ H1^T, K=256 ----
    float4_ acc2[4][4] = {};
    const unsigned short* w2 = a.w2t + (size_t)t * 65536;
    for (int ks = 0; ks < 8; ++ks) {
        short8 af[4], bfr[4];
        for (int mt = 0; mt < 4; ++mt) {
            int hid = w * 64 + mt * 16 + l;
            af[mt] = *(const short8*)(w2 + hid * 256 + ks * 32 + q * 8);
        }
        for (int nt = 0; nt < 4; ++nt) {
            int v = nt * 16 + l;
            bfr[nt] = *(const short8*)(sF + v * 512 + (((ks * 4 + q) ^ (v & 7)) * 16));
        }
        for (int mt = 0; mt < 4; ++mt)
            for (int nt = 0; nt < 4; ++nt)
                acc2[mt][nt] = __builtin_amdgcn_mfma_f32_16x16x32_bf16(
                    af[mt], bfr[nt], acc2[mt][nt], 0, 0, 0);
    }
    __syncthreads();   // all h1 reads done before in-place overwrite with h2

    for (int mt = 0; mt < 4; ++mt)
        for (int nt = 0; nt < 4; ++nt) {
            int v = nt * 16 + l;
            int hu8 = w * 16 + mt * 4 + q;
            int ku16 = hu8 >> 1, par = hu8 & 1;
            uint2 pk;
            pk.x = (unsigned)f2bf(fmaxf(acc2[mt][nt][0], 0.0f)) |
                   ((unsigned)f2bf(fmaxf(acc2[mt][nt][1], 0.0f)) << 16);
            pk.y = (unsigned)f2bf(fmaxf(acc2[mt][nt][2], 0.0f)) |
                   ((unsigned)f2bf(fmaxf(acc2[mt][nt][3], 0.0f)) << 16);
            *(uint2*)(sF + v * 512 + ((ku16 ^ (v & 7)) * 16) + par * 8) = pk;
        }
    __syncthreads();

    // ---- layer 3: out^T[16(3) x 64v], wave w owns vertex tile w, full K ----
    float4_ acc3 = {};
    const unsigned short* w3 = a.w3t + (size_t)t * 4096;
    int v3 = w * 16 + l;
    for (int ks = 0; ks < 8; ++ks) {
        short8 a3 = *(const short8*)(w3 + l * 256 + ks * 32 + q * 8);
        short8 b3 = *(const short8*)(sF + v3 * 512 + (((ks * 4 + q) ^ (v3 & 7)) * 16));
        acc3 = __builtin_amdgcn_mfma_f32_16x16x32_bf16(a3, b3, acc3, 0, 0, 0);
    }
    // D[m=q*4+r][n=l]: q==0 lanes hold outdims 0..3 for vertex v3
    if (q == 0) {
        int m = i0 + v3;
        if (m < cnt) {
            float* o = a.out + (size_t)sidx[v3] * 3;
            o[0] = acc3[0]; o[1] = acc3[1]; o[2] = acc3[2];
        }
    }
}

// ---------------------------------------------------------------------------
extern "C" void kernel_launch(void* const* d_in, const int* in_sizes, int n_in,
                              void* d_out, int out_size, void* d_ws, size_t ws_size,
                              hipStream_t stream) {
    const float* imgs    = (const float*)d_in[0];
    const float* pros    = (const float*)d_in[1];
    const float* x_verts = (const float*)d_in[2];
    const float* W1      = (const float*)d_in[3];
    const float* W2      = (const float*)d_in[4];
    const float* W3      = (const float*)d_in[5];
    const int* imgbatch  = (const int*)d_in[6];
    const int* gar       = (const int*)d_in[7];

    // ws layout (16B-aligned): w1t | w2t | w3t | garf
    unsigned short* w1t = (unsigned short*)d_ws;                       // 589824 B
    unsigned short* w2t = (unsigned short*)((char*)d_ws + 589824);     // 786432 B
    unsigned short* w3t = (unsigned short*)((char*)d_ws + 1376256);    // 49152 B
    float* garf         = (float*)((char*)d_ws + 1425408);             // 6144 B

    prep_garf<<<GARF_BLOCKS + PREP_BLOCKS, 256, 0, stream>>>(
        imgs, pros, imgbatch, W1, W2, W3, w1t, w2t, w3t, garf);

    MoEArgs a;
    a.x_verts = x_verts;
    a.gar = gar;
    for (int t = 0; t < 6; ++t) a.idx[t] = (const int*)d_in[8 + t];
    a.w1t = w1t; a.w2t = w2t; a.w3t = w3t;
    a.garf = garf;
    a.out = (float*)d_out;
    int tiles = 0;
    for (int t = 0; t < 6; ++t) {
        a.cnt[t] = in_sizes[8 + t];
        tiles += (a.cnt[t] + 63) / 64;
        a.tile_end[t] = tiles;
    }
    moe_kernel<<<tiles, 256, 0, stream>>>(a);
}